// Round 5
// baseline (175.473 us; speedup 1.0000x reference)
//
#include <hip/hip_runtime.h>
#include <hip/hip_bf16.h>

typedef float f32x4 __attribute__((ext_vector_type(4)));
typedef __bf16 bf16x8 __attribute__((ext_vector_type(8)));

#define N 8192
#define CH 256
#define NJC 4            // j-chunks
#define JCW (N / NJC)    // 2048 j per chunk
#define JT 128           // j per tile
#define NT (JCW / JT)    // 16 tiles
#define BM 32            // rows per block

// ---- workspace layout (bytes) ----
static constexpr size_t OFF_P1 = 0;
static constexpr size_t OFF_P2 = 32768;
static constexpr size_t OFF_T1 = 65536;
static constexpr size_t OFF_T2 = 66560;
static constexpr size_t OFF_F1 = 67584;
static constexpr size_t OFF_F2 = OFF_F1 + (size_t)N * 4;
static constexpr size_t OFF_XT = 262144;                       // 4 MB
static constexpr size_t OFF_SP = OFF_XT + (size_t)CH * N * 2;  // 4x8192 f32
static constexpr size_t OFF_PV = OFF_SP + (size_t)NJC * N * 4; // 3x8 MB

// K1a: partial t-vectors over h-slices of 8.
__global__ __launch_bounds__(256) void k1a(
    const float* __restrict__ W, const float* __restrict__ w1,
    const float* __restrict__ w2, float* __restrict__ p1, float* __restrict__ p2)
{
    int b = blockIdx.x, c = threadIdx.x;
    float a1 = 0.f, a2 = 0.f;
#pragma unroll
    for (int hh = 0; hh < 8; ++hh) {
        int h = b * 8 + hh;
        float wv = W[h * CH + c];
        a1 = __builtin_fmaf(w1[h], wv, a1);
        a2 = __builtin_fmaf(w2[h], wv, a2);
    }
    p1[b * CH + c] = a1;
    p2[b * CH + c] = a2;
}

// K1b: fold 32 partials -> t1,t2.
__global__ __launch_bounds__(256) void k1b(
    const float* __restrict__ p1, const float* __restrict__ p2,
    float* __restrict__ t1, float* __restrict__ t2)
{
    int c = threadIdx.x;
    float a1 = 0.f, a2 = 0.f;
#pragma unroll 8
    for (int b = 0; b < 32; ++b) { a1 += p1[b * CH + c]; a2 += p2[b * CH + c]; }
    t1[c] = a1;
    t2[c] = a2;
}

// K2: f1[i] = inlayer[i,:]·t1 + b1 ; f2[i] likewise. One wave per row.
__global__ __launch_bounds__(256) void k2_f(
    const float4* __restrict__ x4, const float* __restrict__ t1,
    const float* __restrict__ t2, const float* __restrict__ b1,
    const float* __restrict__ b2, float* __restrict__ f1, float* __restrict__ f2)
{
    int lane = threadIdx.x & 63, wid = threadIdx.x >> 6;
    int row = blockIdx.x * 4 + wid;
    float4 x = x4[(size_t)row * 64 + lane];
    const float4* t1v = (const float4*)t1;
    const float4* t2v = (const float4*)t2;
    float4 ta = t1v[lane], tb = t2v[lane];
    float d1 = x.x * ta.x + x.y * ta.y + x.z * ta.z + x.w * ta.w;
    float d2 = x.x * tb.x + x.y * tb.y + x.z * tb.z + x.w * tb.w;
#pragma unroll
    for (int off = 32; off; off >>= 1) {
        d1 += __shfl_down(d1, off);
        d2 += __shfl_down(d2, off);
    }
    if (lane == 0) { f1[row] = d1 + b1[0]; f2[row] = d2 + b2[0]; }
}

// KT: transpose inlayer [N][CH] f32 -> xt [CH][N] bf16.
__global__ __launch_bounds__(256) void kt_transpose(
    const float* __restrict__ x, unsigned short* __restrict__ xt)
{
    __shared__ unsigned short tile[64][66];
    int jb = (blockIdx.x & 127) * 64;
    int cb = (blockIdx.x >> 7) * 64;
    int t = threadIdx.x;
    int c = t & 63;
#pragma unroll
    for (int it = 0; it < 16; ++it) {
        int r = it * 4 + (t >> 6);
        float v = x[(size_t)(jb + r) * CH + cb + c];
        __hip_bfloat16 h = __float2bfloat16(v);
        tile[c][r] = *reinterpret_cast<unsigned short*>(&h);
    }
    __syncthreads();
#pragma unroll
    for (int it = 0; it < 16; ++it) {
        int cl = it * 4 + (t >> 6);
        xt[(size_t)(cb + cl) * N + jb + c] = tile[cl][c];
    }
}

// Raw barrier: LDS visibility only; global prefetches stay in flight (T4).
#define BAR() { asm volatile("s_waitcnt lgkmcnt(0)" ::: "memory"); \
                __builtin_amdgcn_s_barrier(); }

// K34 v5: BM=32 rows x 2048-j chunk per block, 512 threads (8 waves).
// f2 chunk staged in LDS once. 2-deep adj reg prefetch survives barriers
// (raw s_barrier + lgkmcnt-only wait). P double-buffered, XOR-swizzled:
// 16B unit(row, jslot) = row*16 + (jslot ^ (row&7)).
__global__ __launch_bounds__(512, 2) void k34_fused(
    const int* __restrict__ adj, const float* __restrict__ f1,
    const float* __restrict__ f2, const unsigned short* __restrict__ xt,
    float* __restrict__ pv0, float* __restrict__ pvx, float* __restrict__ s_part)
{
    __shared__ __align__(16) unsigned short P[2][BM * JT];   // 2 x 8 KB
    __shared__ __align__(16) float f2s[JCW];                 // 8 KB

    const int tid = threadIdx.x;
    const int lane = tid & 63;
    const int w = tid >> 6;              // ch-group 0..7
    const int r = lane & 15, q = lane >> 4;
    const int bid = blockIdx.x;
    const int jc = bid & 3;              // j-chunk (bid%8 = XCD -> L2 affinity)
    const int rb = (bid >> 2) * BM;
    const int jbase = jc * JCW;

    // producer role: row = tid>>4 (0..31), 8 j's at (tid&15)*8
    const int prow = tid >> 4;
    const int pjo = (tid & 15) * 8;
    const float f1r = f1[rb + prow];
    const int* aptr = adj + (size_t)(rb + prow) * N + jbase + pjo;
    const int wunit = prow * 16 + ((tid & 15) ^ (prow & 7));

    // consumer role
    const unsigned short* xb0 = xt + (size_t)(w * 32 + r) * N + jbase + q * 8;
    const unsigned short* xb1 = xb0 + (size_t)16 * N;

    // stage f2 chunk into LDS
    *(float4*)(&f2s[tid * 4]) = *(const float4*)(f2 + jbase + tid * 4);

    f32x4 acc[2][2];
#pragma unroll
    for (int mt = 0; mt < 2; ++mt)
#pragma unroll
        for (int nt = 0; nt < 2; ++nt) acc[mt][nt] = (f32x4){0.f, 0.f, 0.f, 0.f};
    float s_acc = 0.f;

    int4 RA0, RA1, RB0, RB1;

#define LOAD_A(R0, R1, t)                                           \
    { const int4* p_ = (const int4*)(aptr + (size_t)(t) * JT);      \
      R0 = p_[0]; R1 = p_[1]; }
#define EXPW(Ra, Rb, buf, tt)                                       \
    { float4 g0 = *(const float4*)(&f2s[(tt) * JT + pjo]);          \
      float4 g1 = *(const float4*)(&f2s[(tt) * JT + pjo + 4]);      \
      int av[8] = {Ra.x, Ra.y, Ra.z, Ra.w, Rb.x, Rb.y, Rb.z, Rb.w}; \
      float gv[8] = {g0.x, g0.y, g0.z, g0.w, g1.x, g1.y, g1.z, g1.w};\
      bf16x8 pk;                                                    \
      _Pragma("unroll")                                             \
      for (int e = 0; e < 8; ++e) {                                 \
          float t_ = f1r + gv[e];                                   \
          t_ = fmaxf(t_, 0.01f * t_);                               \
          float p_ = (av[e] > 0) ? __expf(t_) : 0.f;                \
          s_acc += p_;                                              \
          pk[e] = (__bf16)p_;                                       \
      }                                                             \
      *reinterpret_cast<bf16x8*>(&P[buf][(size_t)wunit * 8]) = pk; }
#define MFMA_TILE(tt, buf)                                          \
    { _Pragma("unroll")                                             \
      for (int kk = 0; kk < 4; ++kk) {                              \
          bf16x8 B0 = *(const bf16x8*)(xb0 + (size_t)(tt) * JT + kk * 32); \
          bf16x8 B1 = *(const bf16x8*)(xb1 + (size_t)(tt) * JT + kk * 32); \
          _Pragma("unroll")                                         \
          for (int mt = 0; mt < 2; ++mt) {                          \
              int u_ = (mt * 16 + r) * 16 + ((kk * 4 + q) ^ (r & 7));\
              bf16x8 A = *(const bf16x8*)(&P[buf][(size_t)u_ * 8]); \
              acc[mt][0] = __builtin_amdgcn_mfma_f32_16x16x32_bf16(A, B0, acc[mt][0], 0, 0, 0); \
              acc[mt][1] = __builtin_amdgcn_mfma_f32_16x16x32_bf16(A, B1, acc[mt][1], 0, 0, 0); \
          }                                                         \
      } }

    // prologue: f2s visible, then P[0]
    LOAD_A(RA0, RA1, 0);
    LOAD_A(RB0, RB1, 1);
    __syncthreads();                      // f2s staged (full drain OK, once)
    EXPW(RA0, RA1, 0, 0);
    BAR();

    for (int t = 0; t < NT; t += 2) {
        if (t + 2 < NT) LOAD_A(RA0, RA1, t + 2);
        MFMA_TILE(t, 0);
        EXPW(RB0, RB1, 1, t + 1);
        BAR();
        if (t + 3 < NT) LOAD_A(RB0, RB1, t + 3);
        MFMA_TILE(t + 1, 1);
        if (t + 2 < NT) EXPW(RA0, RA1, 0, t + 2);
        BAR();
    }

    // row-sum partial: 16 threads per row (consecutive lanes)
    s_acc += __shfl_xor(s_acc, 1);
    s_acc += __shfl_xor(s_acc, 2);
    s_acc += __shfl_xor(s_acc, 4);
    s_acc += __shfl_xor(s_acc, 8);
    if ((lane & 15) == 0) s_part[jc * N + rb + prow] = s_acc;

    // write PV partial. D layout: col = lane&15, row = (lane>>4)*4 + reg
    float* dst = (jc == 0) ? pv0 : (pvx + (size_t)(jc - 1) * N * CH);
#pragma unroll
    for (int mt = 0; mt < 2; ++mt)
#pragma unroll
        for (int nt = 0; nt < 2; ++nt)
#pragma unroll
            for (int reg = 0; reg < 4; ++reg) {
                int row = rb + mt * 16 + q * 4 + reg;
                int col = w * 32 + nt * 16 + r;
                dst[(size_t)row * CH + col] = acc[mt][nt][reg];
            }
#undef LOAD_A
#undef EXPW
#undef MFMA_TILE
}

// K5: out[i][c] = (sum_k pv_k) * inv(sum_k s_k). pv0 lives in d_out.
__global__ __launch_bounds__(256) void k5_reduce(
    const float* __restrict__ pvx, const float* __restrict__ s_part,
    float* __restrict__ out)
{
    int g = blockIdx.x * 256 + threadIdx.x;      // float4 index
    int row = g >> 6;
    float s = s_part[row] + s_part[N + row] + s_part[2 * N + row] + s_part[3 * N + row];
    float inv = (s != 0.f) ? 1.0f / s : 0.f;
    float4* out4 = (float4*)out;
    const float4* p1 = (const float4*)pvx;
    const float4* p2 = p1 + (size_t)N * CH / 4;
    const float4* p3 = p2 + (size_t)N * CH / 4;
    float4 v = out4[g];
    float4 a = p1[g], b = p2[g], c = p3[g];
    v.x = (v.x + a.x + b.x + c.x) * inv;
    v.y = (v.y + a.y + b.y + c.y) * inv;
    v.z = (v.z + a.z + b.z + c.z) * inv;
    v.w = (v.w + a.w + b.w + c.w) * inv;
    out4[g] = v;
}

extern "C" void kernel_launch(void* const* d_in, const int* in_sizes, int n_in,
                              void* d_out, int out_size, void* d_ws, size_t ws_size,
                              hipStream_t stream)
{
    const float* inlayer = (const float*)d_in[0];
    const int*   adj     = (const int*)d_in[1];
    const float* W       = (const float*)d_in[2];
    const float* w1      = (const float*)d_in[3];
    const float* b1      = (const float*)d_in[4];
    const float* w2      = (const float*)d_in[5];
    const float* b2      = (const float*)d_in[6];
    float* out = (float*)d_out;

    char* ws = (char*)d_ws;
    float* p1 = (float*)(ws + OFF_P1);
    float* p2 = (float*)(ws + OFF_P2);
    float* t1 = (float*)(ws + OFF_T1);
    float* t2 = (float*)(ws + OFF_T2);
    float* f1 = (float*)(ws + OFF_F1);
    float* f2 = (float*)(ws + OFF_F2);
    unsigned short* xt = (unsigned short*)(ws + OFF_XT);
    float* s_part = (float*)(ws + OFF_SP);
    float* pvx = (float*)(ws + OFF_PV);

    k1a<<<dim3(32), dim3(256), 0, stream>>>(W, w1, w2, p1, p2);
    kt_transpose<<<dim3(512), dim3(256), 0, stream>>>(inlayer, xt);
    k1b<<<dim3(1), dim3(256), 0, stream>>>(p1, p2, t1, t2);
    k2_f<<<dim3(N / 4), dim3(256), 0, stream>>>(
        (const float4*)inlayer, t1, t2, b1, b2, f1, f2);
    k34_fused<<<dim3((N / BM) * NJC), dim3(512), 0, stream>>>(
        adj, f1, f2, xt, out, pvx, s_part);
    k5_reduce<<<dim3(N * CH / 4 / 256), dim3(256), 0, stream>>>(pvx, s_part, out);
}

// Round 6
// 110.532 us; speedup vs baseline: 1.5875x; 1.5875x over previous
//
#include <hip/hip_runtime.h>
#include <hip/hip_bf16.h>

typedef float f32x4 __attribute__((ext_vector_type(4)));
typedef __bf16 bf16x8 __attribute__((ext_vector_type(8)));

#define N 8192
#define CH 256
#define NJC 4            // j-chunks
#define JCW (N / NJC)    // 2048 j per chunk
#define JT 128           // j per tile
#define NT (JCW / JT)    // 16 tiles per chunk
#define BM 64            // rows per block

// ---- workspace layout (bytes) ----
static constexpr size_t OFF_P1 = 0;
static constexpr size_t OFF_P2 = 32768;
static constexpr size_t OFF_T1 = 65536;
static constexpr size_t OFF_T2 = 66560;
static constexpr size_t OFF_F1 = 67584;
static constexpr size_t OFF_F2 = OFF_F1 + (size_t)N * 4;
static constexpr size_t OFF_XT = 262144;                       // packed B, 4 MB
static constexpr size_t OFF_SP = OFF_XT + (size_t)CH * N * 2;  // 4x8192 f32
static constexpr size_t OFF_PV = OFF_SP + (size_t)NJC * N * 4; // 3x8 MB

// K1a: partial t-vectors over h-slices of 8.
__global__ __launch_bounds__(256) void k1a(
    const float* __restrict__ W, const float* __restrict__ w1,
    const float* __restrict__ w2, float* __restrict__ p1, float* __restrict__ p2)
{
    int b = blockIdx.x, c = threadIdx.x;
    float a1 = 0.f, a2 = 0.f;
#pragma unroll
    for (int hh = 0; hh < 8; ++hh) {
        int h = b * 8 + hh;
        float wv = W[h * CH + c];
        a1 = __builtin_fmaf(w1[h], wv, a1);
        a2 = __builtin_fmaf(w2[h], wv, a2);
    }
    p1[b * CH + c] = a1;
    p2[b * CH + c] = a2;
}

// K1b: fold 32 partials -> t1,t2.
__global__ __launch_bounds__(256) void k1b(
    const float* __restrict__ p1, const float* __restrict__ p2,
    float* __restrict__ t1, float* __restrict__ t2)
{
    int c = threadIdx.x;
    float a1 = 0.f, a2 = 0.f;
#pragma unroll 8
    for (int b = 0; b < 32; ++b) { a1 += p1[b * CH + c]; a2 += p2[b * CH + c]; }
    t1[c] = a1;
    t2[c] = a2;
}

// K2: f1[i] = inlayer[i,:]·t1 + b1 ; f2[i] likewise. One wave per row.
__global__ __launch_bounds__(256) void k2_f(
    const float4* __restrict__ x4, const float* __restrict__ t1,
    const float* __restrict__ t2, const float* __restrict__ b1,
    const float* __restrict__ b2, float* __restrict__ f1, float* __restrict__ f2)
{
    int lane = threadIdx.x & 63, wid = threadIdx.x >> 6;
    int row = blockIdx.x * 4 + wid;
    float4 x = x4[(size_t)row * 64 + lane];
    const float4* t1v = (const float4*)t1;
    const float4* t2v = (const float4*)t2;
    float4 ta = t1v[lane], tb = t2v[lane];
    float d1 = x.x * ta.x + x.y * ta.y + x.z * ta.z + x.w * ta.w;
    float d2 = x.x * tb.x + x.y * tb.y + x.z * tb.z + x.w * tb.w;
#pragma unroll
    for (int off = 32; off; off >>= 1) {
        d1 += __shfl_down(d1, off);
        d2 += __shfl_down(d2, off);
    }
    if (lane == 0) { f1[row] = d1 + b1[0]; f2[row] = d2 + b2[0]; }
}

// KT-pack: inlayer [N][CH] f32 -> xtp fragment-packed bf16 B panel.
// xtp unit index u = (ct*256 + js32)*64 + lane; holds 8 bf16:
//   value[e] = X[j = js32*32 + (lane>>4)*8 + e][c = ct*16 + (lane&15)]
// One block per js32 (32 j-rows), 256 threads.
__global__ __launch_bounds__(256) void kt_pack(
    const float* __restrict__ x, unsigned short* __restrict__ xtp)
{
    __shared__ unsigned short tile[32][264];     // +8 pad
    int js32 = blockIdx.x;
    int jb = js32 * 32;
    int t = threadIdx.x;
#pragma unroll
    for (int it = 0; it < 8; ++it) {
        int lin = it * 256 + t;
        int jr = lin >> 6;            // 0..31
        int cq = lin & 63;            // float4 col
        float4 v = *(const float4*)(x + (size_t)(jb + jr) * CH + cq * 4);
        __hip_bfloat16 h0 = __float2bfloat16(v.x);
        __hip_bfloat16 h1 = __float2bfloat16(v.y);
        __hip_bfloat16 h2 = __float2bfloat16(v.z);
        __hip_bfloat16 h3 = __float2bfloat16(v.w);
        tile[jr][cq * 4 + 0] = *(unsigned short*)&h0;
        tile[jr][cq * 4 + 1] = *(unsigned short*)&h1;
        tile[jr][cq * 4 + 2] = *(unsigned short*)&h2;
        tile[jr][cq * 4 + 3] = *(unsigned short*)&h3;
    }
    __syncthreads();
    int lane = t & 63;
    int r = lane & 15, q = lane >> 4;
#pragma unroll
    for (int pass = 0; pass < 4; ++pass) {
        int ct = pass * 4 + (t >> 6);
        unsigned short vs[8];
#pragma unroll
        for (int e = 0; e < 8; ++e) vs[e] = tile[q * 8 + e][ct * 16 + r];
        size_t u = ((size_t)ct * 256 + js32) * 64 + lane;
        *(ulonglong2*)(xtp + u * 8) = *(ulonglong2*)vs;
    }
}

// Raw barrier: LDS visibility only; global prefetches stay in flight (T4).
#define BAR() { asm volatile("s_waitcnt lgkmcnt(0)" ::: "memory"); \
                __builtin_amdgcn_s_barrier(); }

// K34 v6: BM=64 rows x 2048-j chunk per block, 512 threads (8 waves = 8
// ch-groups of 32). B from fragment-packed xtp (contiguous 1KB wave loads).
// 2-deep adj reg prefetch; P double-buffered in LDS, XOR-swizzled
// (unit = row*16 + (slot ^ (row&7))); f2 chunk staged in LDS.
__global__ __launch_bounds__(512, 4) void k34_fused(
    const int* __restrict__ adj, const float* __restrict__ f1,
    const float* __restrict__ f2, const unsigned short* __restrict__ xtp,
    float* __restrict__ pv0, float* __restrict__ pvx, float* __restrict__ s_part)
{
    __shared__ __align__(16) unsigned short P[2][BM * JT];   // 2 x 16 KB
    __shared__ __align__(16) float f2s[JCW];                 // 8 KB

    const int tid = threadIdx.x;
    const int lane = tid & 63;
    const int w = tid >> 6;              // ch-group 0..7
    const int r = lane & 15, q = lane >> 4;
    const int bid = blockIdx.x;
    const int jc = bid & 3;              // j-chunk (XCD L2 affinity)
    const int rb = (bid >> 2) * BM;
    const int jbase = jc * JCW;

    // producer role: row = tid>>3 (0..63), 16 j's at (tid&7)*16
    const int prow = tid >> 3;
    const int pjo = (tid & 7) * 16;
    const float f1r = f1[rb + prow];
    const int* aptr = adj + (size_t)(rb + prow) * N + jbase + pjo;
    const int s0i = (tid & 7) * 2;
    const int wu0 = prow * 16 + (s0i ^ (prow & 7));
    const int wu1 = prow * 16 + ((s0i + 1) ^ (prow & 7));

    // consumer role: wave w covers cts {w*2, w*2+1}; js32 base for chunk
    const unsigned short* xb0 = xtp + (((size_t)(w * 2) * 256 + jc * 64) * 64 + lane) * 8;
    const unsigned short* xb1 = xtp + (((size_t)(w * 2 + 1) * 256 + jc * 64) * 64 + lane) * 8;

    // stage f2 chunk into LDS
    *(float4*)(&f2s[tid * 4]) = *(const float4*)(f2 + jbase + tid * 4);

    f32x4 acc[4][2];
#pragma unroll
    for (int mt = 0; mt < 4; ++mt)
#pragma unroll
        for (int nt = 0; nt < 2; ++nt) acc[mt][nt] = (f32x4){0.f, 0.f, 0.f, 0.f};
    float s_acc = 0.f;

    int4 RA0, RA1, RA2, RA3, RB0, RB1, RB2, RB3;

#define LOAD_A(R0, R1, R2, R3, t)                                   \
    { const int4* p_ = (const int4*)(aptr + (size_t)(t) * JT);      \
      R0 = p_[0]; R1 = p_[1]; R2 = p_[2]; R3 = p_[3]; }
#define EXPW(R0, R1, R2, R3, buf, tt)                               \
    { float4 g0 = *(const float4*)(&f2s[(tt) * JT + pjo]);          \
      float4 g1 = *(const float4*)(&f2s[(tt) * JT + pjo + 4]);      \
      float4 g2 = *(const float4*)(&f2s[(tt) * JT + pjo + 8]);      \
      float4 g3 = *(const float4*)(&f2s[(tt) * JT + pjo + 12]);     \
      int av[16] = {R0.x, R0.y, R0.z, R0.w, R1.x, R1.y, R1.z, R1.w, \
                    R2.x, R2.y, R2.z, R2.w, R3.x, R3.y, R3.z, R3.w};\
      float gv[16] = {g0.x, g0.y, g0.z, g0.w, g1.x, g1.y, g1.z, g1.w,\
                      g2.x, g2.y, g2.z, g2.w, g3.x, g3.y, g3.z, g3.w};\
      bf16x8 pk0, pk1;                                              \
      _Pragma("unroll")                                             \
      for (int e = 0; e < 16; ++e) {                                \
          float t_ = f1r + gv[e];                                   \
          t_ = fmaxf(t_, 0.01f * t_);                               \
          float p_ = (av[e] > 0) ? __expf(t_) : 0.f;                \
          s_acc += p_;                                              \
          if (e < 8) pk0[e] = (__bf16)p_; else pk1[e - 8] = (__bf16)p_; \
      }                                                             \
      *reinterpret_cast<bf16x8*>(&P[buf][(size_t)wu0 * 8]) = pk0;   \
      *reinterpret_cast<bf16x8*>(&P[buf][(size_t)wu1 * 8]) = pk1; }
#define MFMA_TILE(tt, buf)                                          \
    { _Pragma("unroll")                                             \
      for (int kk = 0; kk < 4; ++kk) {                              \
          bf16x8 B0 = *(const bf16x8*)(xb0 + ((size_t)((tt) * 4 + kk) * 64) * 8); \
          bf16x8 B1 = *(const bf16x8*)(xb1 + ((size_t)((tt) * 4 + kk) * 64) * 8); \
          _Pragma("unroll")                                         \
          for (int mt = 0; mt < 4; ++mt) {                          \
              int u_ = (mt * 16 + r) * 16 + ((kk * 4 + q) ^ (r & 7)); \
              bf16x8 A = *(const bf16x8*)(&P[buf][(size_t)u_ * 8]); \
              acc[mt][0] = __builtin_amdgcn_mfma_f32_16x16x32_bf16(A, B0, acc[mt][0], 0, 0, 0); \
              acc[mt][1] = __builtin_amdgcn_mfma_f32_16x16x32_bf16(A, B1, acc[mt][1], 0, 0, 0); \
          }                                                         \
      } }

    // prologue
    LOAD_A(RA0, RA1, RA2, RA3, 0);
    LOAD_A(RB0, RB1, RB2, RB3, 1);
    __syncthreads();                      // f2s staged (full drain once)
    EXPW(RA0, RA1, RA2, RA3, 0, 0);
    BAR();

    for (int t = 0; t < NT; t += 2) {
        if (t + 2 < NT) LOAD_A(RA0, RA1, RA2, RA3, t + 2);
        MFMA_TILE(t, 0);
        EXPW(RB0, RB1, RB2, RB3, 1, t + 1);
        BAR();
        if (t + 3 < NT) LOAD_A(RB0, RB1, RB2, RB3, t + 3);
        MFMA_TILE(t + 1, 1);
        if (t + 2 < NT) EXPW(RA0, RA1, RA2, RA3, 0, t + 2);
        BAR();
    }

    // row-sum partial: 8 threads per row (consecutive lanes)
    s_acc += __shfl_xor(s_acc, 1);
    s_acc += __shfl_xor(s_acc, 2);
    s_acc += __shfl_xor(s_acc, 4);
    if ((lane & 7) == 0) s_part[jc * N + rb + prow] = s_acc;

    // write PV partial. D layout: col = lane&15, row = (lane>>4)*4 + reg
    float* dst = (jc == 0) ? pv0 : (pvx + (size_t)(jc - 1) * N * CH);
#pragma unroll
    for (int mt = 0; mt < 4; ++mt)
#pragma unroll
        for (int nt = 0; nt < 2; ++nt)
#pragma unroll
            for (int reg = 0; reg < 4; ++reg) {
                int row = rb + mt * 16 + q * 4 + reg;
                int col = w * 32 + nt * 16 + r;
                dst[(size_t)row * CH + col] = acc[mt][nt][reg];
            }
#undef LOAD_A
#undef EXPW
#undef MFMA_TILE
}

// K5: out[i][c] = (sum_k pv_k) * inv(sum_k s_k). pv0 lives in d_out.
__global__ __launch_bounds__(256) void k5_reduce(
    const float* __restrict__ pvx, const float* __restrict__ s_part,
    float* __restrict__ out)
{
    int g = blockIdx.x * 256 + threadIdx.x;      // float4 index
    int row = g >> 6;
    float s = s_part[row] + s_part[N + row] + s_part[2 * N + row] + s_part[3 * N + row];
    float inv = (s != 0.f) ? 1.0f / s : 0.f;
    float4* out4 = (float4*)out;
    const float4* p1 = (const float4*)pvx;
    const float4* p2 = p1 + (size_t)N * CH / 4;
    const float4* p3 = p2 + (size_t)N * CH / 4;
    float4 v = out4[g];
    float4 a = p1[g], b = p2[g], c = p3[g];
    v.x = (v.x + a.x + b.x + c.x) * inv;
    v.y = (v.y + a.y + b.y + c.y) * inv;
    v.z = (v.z + a.z + b.z + c.z) * inv;
    v.w = (v.w + a.w + b.w + c.w) * inv;
    out4[g] = v;
}

extern "C" void kernel_launch(void* const* d_in, const int* in_sizes, int n_in,
                              void* d_out, int out_size, void* d_ws, size_t ws_size,
                              hipStream_t stream)
{
    const float* inlayer = (const float*)d_in[0];
    const int*   adj     = (const int*)d_in[1];
    const float* W       = (const float*)d_in[2];
    const float* w1      = (const float*)d_in[3];
    const float* b1      = (const float*)d_in[4];
    const float* w2      = (const float*)d_in[5];
    const float* b2      = (const float*)d_in[6];
    float* out = (float*)d_out;

    char* ws = (char*)d_ws;
    float* p1 = (float*)(ws + OFF_P1);
    float* p2 = (float*)(ws + OFF_P2);
    float* t1 = (float*)(ws + OFF_T1);
    float* t2 = (float*)(ws + OFF_T2);
    float* f1 = (float*)(ws + OFF_F1);
    float* f2 = (float*)(ws + OFF_F2);
    unsigned short* xtp = (unsigned short*)(ws + OFF_XT);
    float* s_part = (float*)(ws + OFF_SP);
    float* pvx = (float*)(ws + OFF_PV);

    k1a<<<dim3(32), dim3(256), 0, stream>>>(W, w1, w2, p1, p2);
    kt_pack<<<dim3(N / 32), dim3(256), 0, stream>>>(inlayer, xtp);
    k1b<<<dim3(1), dim3(256), 0, stream>>>(p1, p2, t1, t2);
    k2_f<<<dim3(N / 4), dim3(256), 0, stream>>>(
        (const float4*)inlayer, t1, t2, b1, b2, f1, f2);
    k34_fused<<<dim3((N / BM) * NJC), dim3(512), 0, stream>>>(
        adj, f1, f2, xtp, out, pvx, s_part);
    k5_reduce<<<dim3(N * CH / 4 / 256), dim3(256), 0, stream>>>(pvx, s_part, out);
}